// Round 9
// baseline (219.152 us; speedup 1.0000x reference)
//
#include <hip/hip_runtime.h>
#include <hip/hip_fp8.h>
#include <stdint.h>

#define EPS 1e-8f

constexpr int C  = 256;     // channels (K dim)
constexpr int HW = 16384;   // pixels per image (M and N dims)
constexpr int BM = 128;     // block M tile
constexpr int NG = 2048;    // n-group width per block (16 q-subtiles of 128)

typedef __attribute__((ext_vector_type(4))) float floatx4;
typedef long long llong2 __attribute__((ext_vector_type(2)));   // 16B = 2 fp8 k-chunks
typedef unsigned char u8;
typedef unsigned int u32;
typedef unsigned long long u64;

__device__ inline u8 f2fp8(float x) {   // OCP e4m3 (gfx950 HW cvt)
    __hip_fp8_e4m3 h(x);
    return h.__x;
}

// ---------------------------------------------------------------------------
// PREP: one pass over a,b -> sumsq_a/b + fp8 fragment arrays, float4 loads.
// Block: 64 pixels x 256 channels; thread (pg = tid&15, tc = tid>>4) covers
// pixels pg*4..+4 (float4) x channels tc*16..+16.
// Fragment layout (matches gemm): slab (g = p>>4, cp = cb>>3) ; element
// (p, cc) at (g*4+cp)*1024 + lane2*16 + half*8 + (cc&7),
// lane2 = (p&15)+((cb&3)<<4), half = (cb>>2)&1, cb = cc>>3.  b normalized, a raw.
__global__ __launch_bounds__(256) void prep_kernel(const float* __restrict__ a,
                                                   const float* __restrict__ b,
                                                   float* __restrict__ sumsq_a,
                                                   float* __restrict__ sumsq_b,
                                                   u8* __restrict__ aF, u8* __restrict__ bF) {
    __shared__ float red[16][65];
    __shared__ float invb_sh[64];
    const int tid = threadIdx.x;
    const int pg = tid & 15, tc = tid >> 4;
    const int p0 = blockIdx.x * 64, pb = pg * 4;

    // ---- b: 16 channels x 4 pixels into regs + per-pixel partial sumsq
    float4 bv[16];
    float ss0 = 0.f, ss1 = 0.f, ss2 = 0.f, ss3 = 0.f;
    #pragma unroll
    for (int i = 0; i < 16; ++i) {
        bv[i] = *(const float4*)&b[(size_t)(tc * 16 + i) * HW + p0 + pb];
        ss0 += bv[i].x * bv[i].x; ss1 += bv[i].y * bv[i].y;
        ss2 += bv[i].z * bv[i].z; ss3 += bv[i].w * bv[i].w;
    }
    red[tc][pb] = ss0; red[tc][pb + 1] = ss1; red[tc][pb + 2] = ss2; red[tc][pb + 3] = ss3;
    __syncthreads();
    if (tid < 64) {
        float B = 0.f;
        #pragma unroll
        for (int j = 0; j < 16; ++j) B += red[j][tid];
        sumsq_b[p0 + tid] = B;
        invb_sh[tid] = 1.0f / (sqrtf(B + EPS) + EPS);
    }
    __syncthreads();

    // ---- b fragment stores (normalized)
    #pragma unroll
    for (int j = 0; j < 4; ++j) {
        int p = p0 + pb + j;
        float inv = invb_sh[pb + j];
        int g = p >> 4;
        #pragma unroll
        for (int h = 0; h < 2; ++h) {           // two 8-channel blocks
            int cb = tc * 2 + h;
            float* base = nullptr; (void)base;
            u64 wv = 0;
            #pragma unroll
            for (int k = 0; k < 8; ++k) {
                float v = (h == 0)
                    ? (k < 4 ? (k==0?bv[0].x:k==1?bv[1].x:k==2?bv[2].x:bv[3].x) : 0.f)
                    : 0.f;
                (void)v;
                // replaced below
                wv = wv;
            }
            // build bytes explicitly (component j of bv[h*8+k])
            wv = 0;
            #pragma unroll
            for (int k = 0; k < 8; ++k) {
                const float4& f = bv[h * 8 + k];
                float v = (j == 0) ? f.x : (j == 1) ? f.y : (j == 2) ? f.z : f.w;
                wv |= (u64)f2fp8(v * inv) << (8 * k);
            }
            int lane2 = (p & 15) + ((cb & 3) << 4);
            *(u64*)(bF + (((size_t)(g * 4 + (cb >> 3))) << 10) + lane2 * 16 + ((cb >> 2) & 1) * 8) = wv;
        }
    }

    // ---- a: load, raw fragments + sumsq partials
    float4 av[16];
    ss0 = ss1 = ss2 = ss3 = 0.f;
    #pragma unroll
    for (int i = 0; i < 16; ++i) {
        av[i] = *(const float4*)&a[(size_t)(tc * 16 + i) * HW + p0 + pb];
        ss0 += av[i].x * av[i].x; ss1 += av[i].y * av[i].y;
        ss2 += av[i].z * av[i].z; ss3 += av[i].w * av[i].w;
    }
    #pragma unroll
    for (int j = 0; j < 4; ++j) {
        int p = p0 + pb + j;
        int g = p >> 4;
        #pragma unroll
        for (int h = 0; h < 2; ++h) {
            int cb = tc * 2 + h;
            u64 wv = 0;
            #pragma unroll
            for (int k = 0; k < 8; ++k) {
                const float4& f = av[h * 8 + k];
                float v = (j == 0) ? f.x : (j == 1) ? f.y : (j == 2) ? f.z : f.w;
                wv |= (u64)f2fp8(v) << (8 * k);
            }
            int lane2 = (p & 15) + ((cb & 3) << 4);
            *(u64*)(aF + (((size_t)(g * 4 + (cb >> 3))) << 10) + lane2 * 16 + ((cb >> 2) & 1) * 8) = wv;
        }
    }
    red[tc][pb] = ss0; red[tc][pb + 1] = ss1; red[tc][pb + 2] = ss2; red[tc][pb + 3] = ss3;
    __syncthreads();
    if (tid < 64) {
        float A = 0.f;
        #pragma unroll
        for (int j = 0; j < 16; ++j) A += red[j][tid];
        sumsq_a[p0 + tid] = A;
    }
}

// ---------------------------------------------------------------------------
// G: fused GEMM + argmax, register-resident A, N-loop over 16 q-subtiles,
// 3-step-deep B prefetch pipeline (4 buffers; buffer idx = cp, target
// (cp+3)&3 — compile-time). 12 loads in flight/lane covers L2 latency
// (~200-300cyc) with ~450cyc of MFMA. One shuffle-reduce + atomicMax per
// row per wave at the end (262K atomics, verified R8).
__global__ __launch_bounds__(256) void gemm_argmax(const u8* __restrict__ aF,
                                                   const u8* __restrict__ bF,
                                                   u64* __restrict__ packed) {
    const int tid = threadIdx.x;
    const int w = tid >> 6, lane = tid & 63;
    const int q4 = lane >> 4, r15 = lane & 15;
    const int wm = w >> 1, wn = w & 1;

    const u32 bid = blockIdx.x;
    const u32 ng = bid & 7;          // n-group -> XCD (L2-resident B)
    const u32 mt = bid >> 3;         // 0..127 M tile
    const int p0 = (int)mt * BM;

    const u8* gA = aF + ((size_t)(mt * 8 + wm * 4) * 4) * 1024 + (u32)lane * 16;
    llong2 Afr[4][4];
    #pragma unroll
    for (int mi = 0; mi < 4; ++mi)
        #pragma unroll
        for (int cp = 0; cp < 4; ++cp)
            Afr[mi][cp] = *(const llong2*)(gA + (u32)(mi * 4 + cp) * 1024);

    const u8* gB = bF + ((size_t)(ng * 128 + wn * 4)) * 4096 + (u32)lane * 16;

    float bestv[4][4];
    u32   bestq[4][4];
    #pragma unroll
    for (int mi = 0; mi < 4; ++mi)
        #pragma unroll
        for (int reg = 0; reg < 4; ++reg) { bestv[mi][reg] = -3.4e38f; bestq[mi][reg] = 0; }

    const u32 qlane = ng * 2048 + wn * 64 + (u32)r15;   // + qt*128 + ni*16

    llong2 Bfr[4][4];
    #pragma unroll
    for (int s = 0; s < 3; ++s)        // preload steps 0,1,2 (qt=0, cp=s)
        #pragma unroll
        for (int ni = 0; ni < 4; ++ni)
            Bfr[s][ni] = *(const llong2*)(gB + ((u32)ni * 4u + (u32)s) * 1024u);

    for (int qt = 0; qt < 16; ++qt) {
        floatx4 acc[4][4] = {};
        #pragma unroll
        for (int cp = 0; cp < 4; ++cp) {
            int s3 = qt * 4 + cp + 3; if (s3 > 63) s3 = 63;
            u32 q3 = (u32)s3 >> 2, c3 = (u32)s3 & 3;
            #pragma unroll
            for (int ni = 0; ni < 4; ++ni)
                Bfr[(cp + 3) & 3][ni] = *(const llong2*)(gB + q3 * 32768u + ((u32)ni * 4u + c3) * 1024u);
            #pragma unroll
            for (int mi = 0; mi < 4; ++mi)
                #pragma unroll
                for (int ni = 0; ni < 4; ++ni)
                    acc[mi][ni] = __builtin_amdgcn_mfma_f32_16x16x32_fp8_fp8(
                        Afr[mi][cp].x, Bfr[cp][ni].x, acc[mi][ni], 0, 0, 0);
            #pragma unroll
            for (int mi = 0; mi < 4; ++mi)
                #pragma unroll
                for (int ni = 0; ni < 4; ++ni)
                    acc[mi][ni] = __builtin_amdgcn_mfma_f32_16x16x32_fp8_fp8(
                        Afr[mi][cp].y, Bfr[cp][ni].y, acc[mi][ni], 0, 0, 0);
        }
        // running argmax update (ascending q scan => strict > keeps first min)
        #pragma unroll
        for (int mi = 0; mi < 4; ++mi)
            #pragma unroll
            for (int ni = 0; ni < 4; ++ni) {
                u32 qc = qlane + (u32)qt * 128 + (u32)ni * 16;
                #pragma unroll
                for (int reg = 0; reg < 4; ++reg) {
                    float v = acc[mi][ni][reg];
                    bool gt = v > bestv[mi][reg];
                    bestv[mi][reg] = gt ? v : bestv[mi][reg];
                    bestq[mi][reg] = gt ? qc : bestq[mi][reg];
                }
            }
    }

    // final: pack, shuffle-reduce over r15 (stays in q4 group), 1 atomic/row/wave
    #pragma unroll
    for (int mi = 0; mi < 4; ++mi)
        #pragma unroll
        for (int reg = 0; reg < 4; ++reg) {
            u32 m = __float_as_uint(bestv[mi][reg]);
            m = m ^ (u32)(((int)m >> 31) | 0x80000000u);   // monotone map
            u64 pk = ((u64)m << 32) | (u64)(0xFFFFFFFFu - bestq[mi][reg]);
            #pragma unroll
            for (int d = 1; d < 16; d <<= 1) {
                u64 o = __shfl_xor((unsigned long long)pk, d);
                pk = o > pk ? o : pk;
            }
            if (r15 == 0)
                atomicMax(&packed[p0 + wm * 64 + mi * 16 + q4 * 4 + reg], pk);
        }
}

// ---------------------------------------------------------------------------
// L (verified R7/R8): loss from the argmax's own similarity value (no gather).
__global__ void loss_kernel(const u64* __restrict__ packed,
                            const float* __restrict__ sumsq_a, const float* __restrict__ sumsq_b,
                            float* __restrict__ out) {
    int p = blockIdx.x * 256 + threadIdx.x;
    u64 pk = packed[p];
    u32 m = (u32)(pk >> 32);
    u32 u = (m & 0x80000000u) ? (m ^ 0x80000000u) : ~m;   // inverse monotone map
    float s = __uint_as_float(u);
    u32 q = 0xFFFFFFFFu - (u32)(pk & 0xFFFFFFFFull);
    float A = sumsq_a[p], B = sumsq_b[q];
    float dot = s * (sqrtf(B + EPS) + EPS);
    float cossim = dot / ((sqrtf(A) + EPS) * (sqrtf(B) + EPS));
    float v = (1.0f - cossim) * (1.0f / (float)HW);
    #pragma unroll
    for (int d = 1; d < 64; d <<= 1) v += __shfl_xor(v, d);
    if ((threadIdx.x & 63) == 0) atomicAdd(out, v);
}

// ---------------------------------------------------------------------------
extern "C" void kernel_launch(void* const* d_in, const int* in_sizes, int n_in,
                              void* d_out, int out_size, void* d_ws, size_t ws_size,
                              hipStream_t stream) {
    const float* a = (const float*)d_in[0];
    const float* b = (const float*)d_in[1];
    float* out = (float*)d_out;
    char* ws = (char*)d_ws;

    u8*    aF      = (u8*)ws;                                    // 4 MB
    u8*    bF      = (u8*)(ws + (size_t)4 * 1024 * 1024);        // 4 MB
    float* sumsq_a = (float*)(ws + (size_t)8 * 1024 * 1024);     // 64 KB
    float* sumsq_b = sumsq_a + HW;
    u64*   packed  = (u64*)(sumsq_b + HW);                       // 128 KB

    hipMemsetAsync(out, 0, sizeof(float), stream);
    hipMemsetAsync(packed, 0, (size_t)HW * sizeof(u64), stream);

    prep_kernel<<<dim3(HW / 64), 256, 0, stream>>>(a, b, sumsq_a, sumsq_b, aF, bF);
    gemm_argmax<<<dim3((HW / BM) * (HW / NG)), 256, 0, stream>>>(aF, bF, packed);
    loss_kernel<<<dim3(HW / 256), 256, 0, stream>>>(packed, sumsq_a, sumsq_b, out);
}

// Round 10
// 166.533 us; speedup vs baseline: 1.3160x; 1.3160x over previous
//
#include <hip/hip_runtime.h>
#include <hip/hip_fp8.h>
#include <stdint.h>

#define EPS 1e-8f

constexpr int C  = 256;     // channels (K dim)
constexpr int HW = 16384;   // pixels per image (M and N dims)
constexpr int BM = 128;     // block M tile
constexpr int NG = 2048;    // n-group width per block (32 q-substeps of 64)

typedef __attribute__((ext_vector_type(4))) float floatx4;
typedef long long llong2 __attribute__((ext_vector_type(2)));   // 16B = 2 fp8 k-chunks
typedef unsigned char u8;
typedef unsigned int u32;
typedef unsigned long long u64;

__device__ inline u8 f2fp8(float x) {   // OCP e4m3 (gfx950 HW cvt)
    __hip_fp8_e4m3 h(x);
    return h.__x;
}

// ---------------------------------------------------------------------------
// PREP: one pass over a,b -> sumsq_a/b + fp8 fragment arrays, float4 loads.
// Block: 64 pixels x 256 channels; thread (pg = tid&15, tc = tid>>4) covers
// pixels pg*4..+4 (float4) x channels tc*16..+16.
// Fragment layout (matches gemm): slab (g = p>>4, cp = cb>>3); element
// (p, cc) at (g*4+cp)*1024 + lane2*16 + half*8 + (cc&7),
// lane2 = (p&15)+((cb&3)<<4), half = (cb>>2)&1, cb = cc>>3.  b normalized, a raw.
__global__ __launch_bounds__(256) void prep_kernel(const float* __restrict__ a,
                                                   const float* __restrict__ b,
                                                   float* __restrict__ sumsq_a,
                                                   float* __restrict__ sumsq_b,
                                                   u8* __restrict__ aF, u8* __restrict__ bF) {
    __shared__ float red[16][65];
    __shared__ float invb_sh[64];
    const int tid = threadIdx.x;
    const int pg = tid & 15, tc = tid >> 4;
    const int p0 = blockIdx.x * 64, pb = pg * 4;

    // ---- b: 16 channels x 4 pixels into regs + per-pixel partial sumsq
    float4 bv[16];
    float ss0 = 0.f, ss1 = 0.f, ss2 = 0.f, ss3 = 0.f;
    #pragma unroll
    for (int i = 0; i < 16; ++i) {
        bv[i] = *(const float4*)&b[(size_t)(tc * 16 + i) * HW + p0 + pb];
        ss0 += bv[i].x * bv[i].x; ss1 += bv[i].y * bv[i].y;
        ss2 += bv[i].z * bv[i].z; ss3 += bv[i].w * bv[i].w;
    }
    red[tc][pb] = ss0; red[tc][pb + 1] = ss1; red[tc][pb + 2] = ss2; red[tc][pb + 3] = ss3;
    __syncthreads();
    if (tid < 64) {
        float B = 0.f;
        #pragma unroll
        for (int j = 0; j < 16; ++j) B += red[j][tid];
        sumsq_b[p0 + tid] = B;
        invb_sh[tid] = 1.0f / (sqrtf(B + EPS) + EPS);
    }
    __syncthreads();

    // ---- b fragment stores (normalized)
    #pragma unroll
    for (int j = 0; j < 4; ++j) {
        int p = p0 + pb + j;
        float inv = invb_sh[pb + j];
        int g = p >> 4;
        #pragma unroll
        for (int h = 0; h < 2; ++h) {           // two 8-channel blocks
            int cb = tc * 2 + h;
            u64 wv = 0;
            #pragma unroll
            for (int k = 0; k < 8; ++k) {
                const float4& f = bv[h * 8 + k];
                float v = (j == 0) ? f.x : (j == 1) ? f.y : (j == 2) ? f.z : f.w;
                wv |= (u64)f2fp8(v * inv) << (8 * k);
            }
            int lane2 = (p & 15) + ((cb & 3) << 4);
            *(u64*)(bF + (((size_t)(g * 4 + (cb >> 3))) << 10) + lane2 * 16 + ((cb >> 2) & 1) * 8) = wv;
        }
    }

    // ---- a: load, raw fragments + sumsq partials
    float4 av[16];
    ss0 = ss1 = ss2 = ss3 = 0.f;
    #pragma unroll
    for (int i = 0; i < 16; ++i) {
        av[i] = *(const float4*)&a[(size_t)(tc * 16 + i) * HW + p0 + pb];
        ss0 += av[i].x * av[i].x; ss1 += av[i].y * av[i].y;
        ss2 += av[i].z * av[i].z; ss3 += av[i].w * av[i].w;
    }
    #pragma unroll
    for (int j = 0; j < 4; ++j) {
        int p = p0 + pb + j;
        int g = p >> 4;
        #pragma unroll
        for (int h = 0; h < 2; ++h) {
            int cb = tc * 2 + h;
            u64 wv = 0;
            #pragma unroll
            for (int k = 0; k < 8; ++k) {
                const float4& f = av[h * 8 + k];
                float v = (j == 0) ? f.x : (j == 1) ? f.y : (j == 2) ? f.z : f.w;
                wv |= (u64)f2fp8(v) << (8 * k);
            }
            int lane2 = (p & 15) + ((cb & 3) << 4);
            *(u64*)(aF + (((size_t)(g * 4 + (cb >> 3))) << 10) + lane2 * 16 + ((cb >> 2) & 1) * 8) = wv;
        }
    }
    red[tc][pb] = ss0; red[tc][pb + 1] = ss1; red[tc][pb + 2] = ss2; red[tc][pb + 3] = ss3;
    __syncthreads();
    if (tid < 64) {
        float A = 0.f;
        #pragma unroll
        for (int j = 0; j < 16; ++j) A += red[j][tid];
        sumsq_a[p0 + tid] = A;
    }
}

// ---------------------------------------------------------------------------
// G: fused GEMM + argmax. Register-resident A; N-loop over 32 q-substeps of
// 64 cols. Wave tile 64x32 (2m x 2n waves): acc[4][2]=32 + Bfr[2][2]=16 +
// Afr[4][4]=64 + best=32 ≈ 160 regs -> 3 waves/SIMD (R9 showed occupancy,
// not pipeline depth, is the lever; R8's 64x64 tile = 200 regs = 2 waves).
// 1-step/2-buffer B prefetch (verified R8). End-only shuffle-reduce +
// atomicMax per row per wave (262K atomics, verified R8: WRITE 8MB).
__global__ __launch_bounds__(256, 3) void gemm_argmax(const u8* __restrict__ aF,
                                                      const u8* __restrict__ bF,
                                                      u64* __restrict__ packed) {
    const int tid = threadIdx.x;
    const int w = tid >> 6, lane = tid & 63;
    const int q4 = lane >> 4, r15 = lane & 15;
    const int wm = w >> 1, wn = w & 1;

    const u32 bid = blockIdx.x;
    const u32 ng = bid & 7;          // n-group -> XCD (L2-resident B)
    const u32 mt = bid >> 3;         // 0..127 M tile
    const int p0 = (int)mt * BM;

    // A fragments resident: frag (mi, cp) = 16B covering k-chunks 2cp,2cp+1
    const u8* gA = aF + ((size_t)(mt * 8 + wm * 4) * 4) * 1024 + (u32)lane * 16;
    llong2 Afr[4][4];
    #pragma unroll
    for (int mi = 0; mi < 4; ++mi)
        #pragma unroll
        for (int cp = 0; cp < 4; ++cp)
            Afr[mi][cp] = *(const llong2*)(gA + (u32)(mi * 4 + cp) * 1024);

    // B: col-group (ng*128 + qt*4 + wn*2 + ni), frag cp -> +cp*1024
    const u8* gB = bF + ((size_t)(ng * 128 + wn * 2)) * 4096 + (u32)lane * 16;

    float bestv[4][4];
    u32   bestq[4][4];
    #pragma unroll
    for (int mi = 0; mi < 4; ++mi)
        #pragma unroll
        for (int reg = 0; reg < 4; ++reg) { bestv[mi][reg] = -3.4e38f; bestq[mi][reg] = 0; }

    const u32 qlane = ng * 2048 + wn * 32 + (u32)r15;   // + qt*64 + ni*16

    llong2 Bfr[2][2];
    #pragma unroll
    for (int ni = 0; ni < 2; ++ni)
        Bfr[0][ni] = *(const llong2*)(gB + (u32)ni * 4096u);

    for (int qt = 0; qt < 32; ++qt) {
        floatx4 acc[4][2] = {};
        #pragma unroll
        for (int cp = 0; cp < 4; ++cp) {
            const int cur = cp & 1, nxt = cur ^ 1;
            // prefetch next step: (qt, cp+1) or (qt+1, 0)
            u32 nqt = (cp == 3) ? (u32)(qt + 1 < 32 ? qt + 1 : 31) : (u32)qt;
            u32 ncp = (cp == 3) ? 0u : (u32)(cp + 1);
            #pragma unroll
            for (int ni = 0; ni < 2; ++ni)
                Bfr[nxt][ni] = *(const llong2*)(gB + nqt * 16384u + (u32)ni * 4096u + ncp * 1024u);
            #pragma unroll
            for (int mi = 0; mi < 4; ++mi)
                #pragma unroll
                for (int ni = 0; ni < 2; ++ni)
                    acc[mi][ni] = __builtin_amdgcn_mfma_f32_16x16x32_fp8_fp8(
                        Afr[mi][cp].x, Bfr[cur][ni].x, acc[mi][ni], 0, 0, 0);
            #pragma unroll
            for (int mi = 0; mi < 4; ++mi)
                #pragma unroll
                for (int ni = 0; ni < 2; ++ni)
                    acc[mi][ni] = __builtin_amdgcn_mfma_f32_16x16x32_fp8_fp8(
                        Afr[mi][cp].y, Bfr[cur][ni].y, acc[mi][ni], 0, 0, 0);
        }
        // running argmax update (ascending q scan => strict > keeps first min)
        #pragma unroll
        for (int mi = 0; mi < 4; ++mi)
            #pragma unroll
            for (int ni = 0; ni < 2; ++ni) {
                u32 qc = qlane + (u32)qt * 64 + (u32)ni * 16;
                #pragma unroll
                for (int reg = 0; reg < 4; ++reg) {
                    float v = acc[mi][ni][reg];
                    bool gt = v > bestv[mi][reg];
                    bestv[mi][reg] = gt ? v : bestv[mi][reg];
                    bestq[mi][reg] = gt ? qc : bestq[mi][reg];
                }
            }
    }

    // final: pack, shuffle-reduce over r15 (stays in q4 group), 1 atomic/row/wave
    #pragma unroll
    for (int mi = 0; mi < 4; ++mi)
        #pragma unroll
        for (int reg = 0; reg < 4; ++reg) {
            u32 m = __float_as_uint(bestv[mi][reg]);
            m = m ^ (u32)(((int)m >> 31) | 0x80000000u);   // monotone map
            u64 pk = ((u64)m << 32) | (u64)(0xFFFFFFFFu - bestq[mi][reg]);
            #pragma unroll
            for (int d = 1; d < 16; d <<= 1) {
                u64 o = __shfl_xor((unsigned long long)pk, d);
                pk = o > pk ? o : pk;
            }
            if (r15 == 0)
                atomicMax(&packed[p0 + wm * 64 + mi * 16 + q4 * 4 + reg], pk);
        }
}

// ---------------------------------------------------------------------------
// L (verified R7/R8): loss from the argmax's own similarity value (no gather).
__global__ void loss_kernel(const u64* __restrict__ packed,
                            const float* __restrict__ sumsq_a, const float* __restrict__ sumsq_b,
                            float* __restrict__ out) {
    int p = blockIdx.x * 256 + threadIdx.x;
    u64 pk = packed[p];
    u32 m = (u32)(pk >> 32);
    u32 u = (m & 0x80000000u) ? (m ^ 0x80000000u) : ~m;   // inverse monotone map
    float s = __uint_as_float(u);
    u32 q = 0xFFFFFFFFu - (u32)(pk & 0xFFFFFFFFull);
    float A = sumsq_a[p], B = sumsq_b[q];
    float dot = s * (sqrtf(B + EPS) + EPS);
    float cossim = dot / ((sqrtf(A) + EPS) * (sqrtf(B) + EPS));
    float v = (1.0f - cossim) * (1.0f / (float)HW);
    #pragma unroll
    for (int d = 1; d < 64; d <<= 1) v += __shfl_xor(v, d);
    if ((threadIdx.x & 63) == 0) atomicAdd(out, v);
}

// ---------------------------------------------------------------------------
extern "C" void kernel_launch(void* const* d_in, const int* in_sizes, int n_in,
                              void* d_out, int out_size, void* d_ws, size_t ws_size,
                              hipStream_t stream) {
    const float* a = (const float*)d_in[0];
    const float* b = (const float*)d_in[1];
    float* out = (float*)d_out;
    char* ws = (char*)d_ws;

    u8*    aF      = (u8*)ws;                                    // 4 MB
    u8*    bF      = (u8*)(ws + (size_t)4 * 1024 * 1024);        // 4 MB
    float* sumsq_a = (float*)(ws + (size_t)8 * 1024 * 1024);     // 64 KB
    float* sumsq_b = sumsq_a + HW;
    u64*   packed  = (u64*)(sumsq_b + HW);                       // 128 KB

    hipMemsetAsync(out, 0, sizeof(float), stream);
    hipMemsetAsync(packed, 0, (size_t)HW * sizeof(u64), stream);

    prep_kernel<<<dim3(HW / 64), 256, 0, stream>>>(a, b, sumsq_a, sumsq_b, aF, bF);
    gemm_argmax<<<dim3((HW / BM) * (HW / NG)), 256, 0, stream>>>(aF, bF, packed);
    loss_kernel<<<dim3(HW / 256), 256, 0, stream>>>(packed, sumsq_a, sumsq_b, out);
}